// Round 15
// baseline (140.983 us; speedup 1.0000x reference)
//
#include <hip/hip_runtime.h>
#include <hip/hip_bf16.h>
#include <math.h>

// BarrierNet fused forward, v13 — SINGLE kernel, zero d_ws use.
// r14->r15: all prior variants kept B-frags in d_ws, which the harness
// re-poisons (256MB @6.7TB/s) before every launch -> prep output always
// HBM-cold + fill-contended. Now: W21/W22 (clean, read-only, 256KB,
// L2-resident) are converted f32->bf16 DURING the LDS staging copy; QP is
// fused as the block tail (stage buffer reused for qC/res; 4-way ordered
// candidate split across the 4 threads/row). No prep, no ps, no ws.

typedef unsigned int u32;
typedef unsigned long long u64;
typedef unsigned short u16;
typedef __attribute__((ext_vector_type(8))) short short8;   // 8 bf16 (MFMA A/B)
typedef __attribute__((ext_vector_type(4))) float f32x4;
typedef __attribute__((ext_vector_type(2))) float f32x2;
typedef __attribute__((ext_vector_type(4))) u32 u32x4;

union Frag { short8 v; u32 u[4]; u32x4 q; };

__device__ __forceinline__ u32 packbf(float a, float b) {
    float2 f2; f2.x = a; f2.y = b;
    __hip_bfloat162 h = __float22bfloat162_rn(f2);   // v_cvt_pk_bf16_f32
    union { __hip_bfloat162 h2; u32 u; } cv; cv.h2 = h;
    return cv.u;
}

__device__ const float OBX[8] = { 10.f, 7.07106781186547524f, 6.123234e-16f, -7.07106781186547524f,
                                 -10.f, -7.07106781186547524f, -1.8369702e-15f, 7.07106781186547524f };
__device__ const float OBY[8] = { 0.f, 7.07106781186547524f, 10.f, 7.07106781186547524f,
                                  1.2246468e-15f, -7.07106781186547524f, -10.f, -7.07106781186547524f };

// triu_indices(9,1) pairs packed as 4-bit nibbles in u64 immediates
#define PI0_ 0x2111111100000000ULL
#define PI1_ 0x5544443333322222ULL
#define PI2_ 0x7665ULL
#define PJ0_ 0x3876543287654321ULL
#define PJ1_ 0x7687658765487654ULL
#define PJ2_ 0x8878ULL
__device__ __forceinline__ int unpack4(u64 w0, u64 w1, u64 w2, int t) {
    u64 w = (t < 16) ? w0 : (t < 32) ? w1 : w2;
    return (int)((w >> ((t & 15) * 4)) & 15);
}

// ---------- fused: layer1 + two MFMA heads + QP ----------
__global__ __launch_bounds__(256)
void barriernet_kernel(const float* __restrict__ x,      // [B,8]
                       const float* __restrict__ meanp,  // [8]
                       const float* __restrict__ stdp,   // [8]
                       const float* __restrict__ W1,     // [256][8]
                       const float* __restrict__ b1,     // [256]
                       const float* __restrict__ W21,    // [128][256]
                       const float* __restrict__ b21,    // [128]
                       const float* __restrict__ W31,    // [2][128]
                       const float* __restrict__ b31,    // [2]
                       const float* __restrict__ W22,    // [128][256]
                       const float* __restrict__ b22,    // [128]
                       const float* __restrict__ W32,    // [2][128]
                       const float* __restrict__ b32,    // [2]
                       float* __restrict__ out, int Btot)
{
    const int tid  = threadIdx.x;
    const int wave = tid >> 6;
    const int lane = tid & 63;
    const int q    = lane >> 4;
    const int m    = lane & 15;
    const int blockRow = blockIdx.x * 64;

    __shared__ u32x4 stage[2048];     // 32 KB; later aliased by qC/res
    __shared__ float lds_p[64][4];

    // ---- input row for this wave's 16 rows
    f32x4 xa0, xb0;
    {
        int R0 = blockRow + wave * 16 + m;
        const f32x4* xv0 = (const f32x4*)(x + (R0 < Btot ? R0 : 0) * 8);
        xa0 = xv0[0]; xb0 = xv0[1];
    }

    const f32x4* W1v = (const f32x4*)W1;
    const f32x4* b1v = (const f32x4*)b1;

    // ---- layer-1 ONCE: A-fragments for all 8 K-steps (32 VGPR)
    Frag A[8];
    #pragma unroll
    for (int ks = 0; ks < 8; ++ks) {
        int kb = ks * 32 + q * 8;
        f32x4 bA = b1v[kb >> 2];
        f32x4 bB = b1v[(kb >> 2) + 1];
        float h0[8];
        #pragma unroll
        for (int j = 0; j < 8; ++j) {
            f32x4 wa = W1v[(kb + j) * 2];
            f32x4 wb = W1v[(kb + j) * 2 + 1];
            float a0 = (j < 4) ? bA[j] : bB[j - 4];
            a0 = fmaf(wa.x, xa0.x, a0);
            a0 = fmaf(wa.y, xa0.y, a0);
            a0 = fmaf(wa.z, xa0.z, a0);
            a0 = fmaf(wa.w, xa0.w, a0);
            a0 = fmaf(wb.x, xb0.x, a0);
            a0 = fmaf(wb.y, xb0.y, a0);
            a0 = fmaf(wb.z, xb0.z, a0);
            a0 = fmaf(wb.w, xb0.w, a0);
            h0[j] = fmaxf(a0, 0.f);
        }
        #pragma unroll
        for (int t = 0; t < 4; ++t)
            A[ks].u[t] = packbf(h0[2 * t], h0[2 * t + 1]);
    }

    // ---- two heads: stage-with-convert W2 (f32, clean d_in) -> LDS bf16 frags
    #pragma unroll 1
    for (int head = 0; head < 2; ++head) {
        const float* W2 = head ? W22 : W21;
        const float* b2 = head ? b22 : b21;
        const float* W3 = head ? W32 : W31;
        const float* b3 = head ? b32 : b31;

        f32x4 acc[8];
        #pragma unroll
        for (int nt = 0; nt < 8; ++nt) acc[nt] = (f32x4){0.f, 0.f, 0.f, 0.f};

        #pragma unroll
        for (int half = 0; half < 2; ++half) {
            // stage frags for ks = half*4 + wave (each wave owns one ks), nt = i
            // frag F = wave*512 + i*64 + lane holds
            //   W2[n = i*16 + m][k = (half*4+wave)*32 + q*8 + j], j=0..7
            {
                int ks = half * 4 + wave;
                int k0 = ks * 32 + q * 8;
                #pragma unroll
                for (int i = 0; i < 8; ++i) {
                    const f32x4* s = (const f32x4*)(W2 + (i * 16 + m) * 256 + k0);
                    f32x4 w0 = s[0], w1 = s[1];
                    u32x4 o;
                    o.x = packbf(w0.x, w0.y);
                    o.y = packbf(w0.z, w0.w);
                    o.z = packbf(w1.x, w1.y);
                    o.w = packbf(w1.z, w1.w);
                    stage[wave * 512 + i * 64 + lane] = o;
                }
            }
            __syncthreads();
            #pragma unroll
            for (int ksl = 0; ksl < 4; ++ksl) {
                const int ks = half * 4 + ksl;        // static (half unrolled)
                Frag Bf[8];
                #pragma unroll
                for (int nt = 0; nt < 8; ++nt)
                    Bf[nt].q = stage[ksl * 512 + nt * 64 + lane];
                #pragma unroll
                for (int nt = 0; nt < 8; ++nt)
                    acc[nt] = __builtin_amdgcn_mfma_f32_16x16x32_bf16(A[ks].v, Bf[nt].v, acc[nt], 0, 0, 0);
            }
            __syncthreads();   // all waves done reading before next stage overwrite
        }

        // ---- epilogue: bias+relu+W3 dot, 16-lane reduce, LDS scatter
        float pr0[4], pr1[4];
        #pragma unroll
        for (int rg = 0; rg < 4; ++rg) { pr0[rg] = 0.f; pr1[rg] = 0.f; }
        #pragma unroll
        for (int nt = 0; nt < 8; ++nt) {
            int col = nt * 16 + m;
            float b2c = b2[col];
            float w0c = W3[col];
            float w1c = W3[128 + col];
            #pragma unroll
            for (int rg = 0; rg < 4; ++rg) {
                float rv = fmaxf(acc[nt][rg] + b2c, 0.f);
                pr0[rg] = fmaf(rv, w0c, pr0[rg]);
                pr1[rg] = fmaf(rv, w1c, pr1[rg]);
            }
        }
        #pragma unroll
        for (int rg = 0; rg < 4; ++rg) {
            float v0 = pr0[rg], v1 = pr1[rg];
            #pragma unroll
            for (int off = 1; off < 16; off <<= 1) {
                v0 += __shfl_xor(v0, off, 64);
                v1 += __shfl_xor(v1, off, 64);
            }
            pr0[rg] = v0; pr1[rg] = v1;
        }
        if (m == 0) {
            #pragma unroll
            for (int rg = 0; rg < 4; ++rg) {
                int row = wave * 16 + q * 4 + rg;
                float a0 = pr0[rg] + b3[0];
                float a1 = pr1[rg] + b3[1];
                if (head == 0) {
                    lds_p[row][0] = a0;
                    lds_p[row][1] = a1;
                } else {
                    lds_p[row][2] = 4.f / (1.f + expf(-a0));
                    lds_p[row][3] = 4.f / (1.f + expf(-a1));
                }
            }
        }
    }
    __syncthreads();

    // ================= QP tail (stage buffer reused) =================
    f32x4 (*qC)[64]  = (f32x4(*)[64])stage;           // 9 KB
    f32x4 (*res)[64] = (f32x4(*)[64])(stage + 576);   // 3 KB, after qC

    const int rq   = tid & 63;
    const int part = tid >> 6;
    const int R    = blockRow + rq;
    float p0 = lds_p[rq][0];
    float p1 = lds_p[rq][1];

    if (part == 0) {
        float s0 = lds_p[rq][2];
        float s1 = lds_p[rq][3];
        float xr[8];
        const float* xp = x + (R < Btot ? R : 0) * 8;
        #pragma unroll
        for (int c = 0; c < 8; ++c) xr[c] = fmaf(xp[c], stdp[c], meanp[c]);
        float px = xr[0], py = xr[1], th = xr[2], v = xr[3];
        float ox = xr[4], oy = xr[5], oth = xr[6], ov = xr[7];
        float st = sinf(th),  ct = cosf(th);
        float so = sinf(oth), co = cosf(oth);
        float vs = v * st, vc = v * ct;
        float sps = s0 + s1, ss = s0 * s1;
        float Lf2b = 2.f * v * v;
        #pragma unroll 1
        for (int k = 0; k < 8; ++k) {
            float dx = px - OBX[k], dy = py - OBY[k];
            float bar  = dx * dx + dy * dy - 0.64f;
            float bdot = 2.f * dx * vc + 2.f * dy * vs;
            float gx = 2.f * dx * vs - 2.f * dy * vc;
            float gy = -(2.f * dx * ct + 2.f * dy * st);
            float hk = Lf2b + sps * bdot + ss * bar;
            float ht = hk + 1e-6f * (1.f + fabsf(hk));
            qC[k][rq] = (f32x4){gx, gy, hk, ht};
        }
        {
            float dxo = px - ox, dyo = py - oy;
            float bar_o  = dxo * dxo + dyo * dyo - 0.25f;
            float bdot_o = 2.f * dxo * (vc - ov * co) + 2.f * dyo * (vs - ov * so);
            float Lf2b_o = 2.f * (v * v + ov * ov + 2.f * v * ov * cosf(th - oth));
            float gx = 2.f * dxo * vs - 2.f * dyo * vc;
            float gy = -(2.f * dxo * ct + 2.f * dyo * st);
            float hk = Lf2b_o + sps * bdot_o + ss * bar_o;
            float ht = hk + 1e-6f * (1.f + fabsf(hk));
            qC[8][rq] = (f32x4){gx, gy, hk, ht};
        }
    }
    __syncthreads();

    // preload the 9 constraints into NAMED registers
    const f32x4 C0 = qC[0][rq], C1 = qC[1][rq], C2 = qC[2][rq];
    const f32x4 C3 = qC[3][rq], C4 = qC[4][rq], C5 = qC[5][rq];
    const f32x4 C6 = qC[6][rq], C7 = qC[7][rq], C8 = qC[8][rq];

    // candidates: 0 unconstrained, 1..9 singles, 10..45 pairs (triu order)
    // 4-way ordered split: [0,12) [12,24) [24,35) [35,46)
    const int c0i = (part == 0) ? 0  : (part == 1) ? 12 : (part == 2) ? 24 : 35;
    const int c1i = (part == 0) ? 12 : (part == 1) ? 24 : (part == 2) ? 35 : 46;
    float bobj = INFINITY;
    float bzx = -p0, bzy = -p1;     // argmin of all-inf -> index 0 -> z0
    #pragma unroll 2
    for (int c = c0i; c < c1i; ++c) {
        float zx, zy;
        bool pre;
        if (c == 0) {
            zx = -p0; zy = -p1; pre = true;
        } else if (c <= 9) {
            f32x4 g = qC[c - 1][rq];                 // one ds_read_b128
            float gg  = g.x * g.x + g.y * g.y;
            float lam = (-(g.x * p0 + g.y * p1) - g.z) / (gg + 1e-12f);
            zx = -p0 - lam * g.x;
            zy = -p1 - lam * g.y;
            pre = (lam >= -1e-8f);
        } else {
            int t = c - 10;
            int pi = unpack4(PI0_, PI1_, PI2_, t);   // scalar, no memory
            int pj = unpack4(PJ0_, PJ1_, PJ2_, t);
            f32x4 gi = qC[pi][rq];                   // two ds_read_b128
            f32x4 gj = qC[pj][rq];
            float det = gi.x * gj.y - gi.y * gj.x;
            bool dok = fabsf(det) > 1e-9f;
            float ds = dok ? det : 1.0f;
            float inv = 1.0f / ds;
            zx = (gi.z * gj.y - gj.z * gi.y) * inv;
            zy = (gi.x * gj.z - gj.x * gi.z) * inv;
            float rx = -(zx + p0), ry = -(zy + p1);
            float li = (gj.y * rx - gj.x * ry) * inv;
            float lj = (gi.x * ry - gi.y * rx) * inv;
            pre = dok && (li >= -1e-8f) && (lj >= -1e-8f);
        }
        bool ok = pre;
        ok = ok && (zx * C0.x + zy * C0.y <= C0.w);
        ok = ok && (zx * C1.x + zy * C1.y <= C1.w);
        ok = ok && (zx * C2.x + zy * C2.y <= C2.w);
        ok = ok && (zx * C3.x + zy * C3.y <= C3.w);
        ok = ok && (zx * C4.x + zy * C4.y <= C4.w);
        ok = ok && (zx * C5.x + zy * C5.y <= C5.w);
        ok = ok && (zx * C6.x + zy * C6.y <= C6.w);
        ok = ok && (zx * C7.x + zy * C7.y <= C7.w);
        ok = ok && (zx * C8.x + zy * C8.y <= C8.w);
        float obj = 0.5f * (zx * zx + zy * zy) + zx * p0 + zy * p1;
        if (ok && obj < bobj) { bobj = obj; bzx = zx; bzy = zy; }
    }

    if (part) {
        res[part - 1][rq] = (f32x4){bobj, bzx, bzy, 0.f};
    }
    __syncthreads();
    if (part == 0) {
        #pragma unroll
        for (int pp = 0; pp < 3; ++pp) {
            f32x4 r = res[pp][rq];
            if (r.x < bobj) { bobj = r.x; bzx = r.y; bzy = r.z; }  // strict <, ordered
        }
        if (R < Btot) {
            f32x2 o2; o2.x = bzx; o2.y = bzy;
            ((f32x2*)out)[R] = o2;
        }
    }
}

extern "C" void kernel_launch(void* const* d_in, const int* in_sizes, int n_in,
                              void* d_out, int out_size, void* d_ws, size_t ws_size,
                              hipStream_t stream) {
    const float* x    = (const float*)d_in[0];
    const float* mean = (const float*)d_in[1];
    const float* stdv = (const float*)d_in[2];
    const float* W1   = (const float*)d_in[3];
    const float* b1   = (const float*)d_in[4];
    const float* W21  = (const float*)d_in[5];
    const float* b21  = (const float*)d_in[6];
    const float* W31  = (const float*)d_in[7];
    const float* b31  = (const float*)d_in[8];
    const float* W22  = (const float*)d_in[9];
    const float* b22  = (const float*)d_in[10];
    const float* W32  = (const float*)d_in[11];
    const float* b32  = (const float*)d_in[12];
    int B = in_sizes[0] / 8;
    float* out = (float*)d_out;

    hipLaunchKernelGGL(barriernet_kernel, dim3((B + 63) / 64), dim3(256), 0, stream,
                       x, mean, stdv, W1, b1, W21, b21, W31, b31,
                       W22, b22, W32, b32, out, B);
}

// Round 16
// 119.691 us; speedup vs baseline: 1.1779x; 1.1779x over previous
//
#include <hip/hip_runtime.h>
#include <hip/hip_bf16.h>
#include <math.h>

// BarrierNet fused forward, v14.
// r15->r16: recombination of measured-good pieces. prep (bf16 B-frags in ws,
// NT store) + ONE fused kernel = r14 gemm body (coalesced bf16 staging, mt=1,
// grid 1024) + r15 QP tail (stage LDS aliased, 4-way ordered candidate split).
// Removes ps round-trip + one launch. Transcendentals -> __sinf/__cosf/__expf
// (r15 showed ~6k VALU inst/thread; libm sin/cos are ~100-inst libcalls).

typedef unsigned int u32;
typedef unsigned long long u64;
typedef unsigned short u16;
typedef __attribute__((ext_vector_type(8))) short short8;   // 8 bf16 (MFMA A/B)
typedef __attribute__((ext_vector_type(4))) float f32x4;
typedef __attribute__((ext_vector_type(2))) float f32x2;
typedef __attribute__((ext_vector_type(4))) u32 u32x4;

union Frag { short8 v; u32 u[4]; u32x4 q; };

__device__ __forceinline__ u32 packbf(float a, float b) {
    float2 f2; f2.x = a; f2.y = b;
    __hip_bfloat162 h = __float22bfloat162_rn(f2);   // v_cvt_pk_bf16_f32
    union { __hip_bfloat162 h2; u32 u; } cv; cv.h2 = h;
    return cv.u;
}

__device__ const float OBX[8] = { 10.f, 7.07106781186547524f, 6.123234e-16f, -7.07106781186547524f,
                                 -10.f, -7.07106781186547524f, -1.8369702e-15f, 7.07106781186547524f };
__device__ const float OBY[8] = { 0.f, 7.07106781186547524f, 10.f, 7.07106781186547524f,
                                  1.2246468e-15f, -7.07106781186547524f, -10.f, -7.07106781186547524f };

// triu_indices(9,1) pairs packed as 4-bit nibbles in u64 immediates
#define PI0_ 0x2111111100000000ULL
#define PI1_ 0x5544443333322222ULL
#define PI2_ 0x7665ULL
#define PJ0_ 0x3876543287654321ULL
#define PJ1_ 0x7687658765487654ULL
#define PJ2_ 0x8878ULL
__device__ __forceinline__ int unpack4(u64 w0, u64 w1, u64 w2, int t) {
    u64 w = (t < 16) ? w0 : (t < 32) ? w1 : w2;
    return (int)((w >> ((t & 15) * 4)) & 15);
}

// ---------- prep: swizzle W2{1,2} (f32 [128][256]) into bf16 B-fragments ----------
// frag f = head*4096 + ks*512 + nt*64 + lane ; j=0..7:
//   W2h[n = nt*16 + (lane&15)][k = ks*32 + (lane>>4)*8 + j]
__global__ __launch_bounds__(256)
void prep_kernel(const float* __restrict__ W21, const float* __restrict__ W22,
                 u32* __restrict__ ws)
{
    int idx  = blockIdx.x * 256 + threadIdx.x;      // 0..8191
    int lane = idx & 63;
    int nt   = (idx >> 6) & 7;
    int ks   = (idx >> 9) & 7;
    int head = idx >> 12;
    const float* W = head ? W22 : W21;
    int n  = nt * 16 + (lane & 15);
    int k0 = ks * 32 + (lane >> 4) * 8;
    const float* s = W + n * 256 + k0;
    u32x4 o;
    o.x = packbf(s[0], s[1]);
    o.y = packbf(s[2], s[3]);
    o.z = packbf(s[4], s[5]);
    o.w = packbf(s[6], s[7]);
    __builtin_nontemporal_store(o, (u32x4*)ws + idx);
}

// ---------- fused: layer1 + two MFMA heads + QP tail ----------
__global__ __launch_bounds__(256)
void barriernet_kernel(const float* __restrict__ x,      // [B,8]
                       const float* __restrict__ meanp,  // [8]
                       const float* __restrict__ stdp,   // [8]
                       const float* __restrict__ W1,     // [256][8]
                       const float* __restrict__ b1,     // [256]
                       const float* __restrict__ b21,    // [128]
                       const float* __restrict__ W31,    // [2][128]
                       const float* __restrict__ b31,    // [2]
                       const float* __restrict__ b22,    // [128]
                       const float* __restrict__ W32,    // [2][128]
                       const float* __restrict__ b32,    // [2]
                       const u32* __restrict__ wsB,      // swizzled bf16 B-frags
                       float* __restrict__ out, int Btot)
{
    const int tid  = threadIdx.x;
    const int wave = tid >> 6;
    const int lane = tid & 63;
    const int q    = lane >> 4;
    const int m    = lane & 15;
    const int blockRow = blockIdx.x * 64;

    __shared__ u32x4 stage[2048];     // 32 KB; aliased by qC/res in the tail
    __shared__ float lds_p[64][4];

    f32x4 xa0, xb0;
    {
        int R0 = blockRow + wave * 16 + m;
        const f32x4* xv0 = (const f32x4*)(x + (R0 < Btot ? R0 : 0) * 8);
        xa0 = xv0[0]; xb0 = xv0[1];
    }

    const f32x4* W1v = (const f32x4*)W1;
    const f32x4* b1v = (const f32x4*)b1;

    // ---- layer-1 ONCE: A-fragments for all 8 K-steps (32 VGPR)
    Frag A[8];
    #pragma unroll
    for (int ks = 0; ks < 8; ++ks) {
        int kb = ks * 32 + q * 8;
        f32x4 bA = b1v[kb >> 2];
        f32x4 bB = b1v[(kb >> 2) + 1];
        float h0[8];
        #pragma unroll
        for (int j = 0; j < 8; ++j) {
            f32x4 wa = W1v[(kb + j) * 2];
            f32x4 wb = W1v[(kb + j) * 2 + 1];
            float a0 = (j < 4) ? bA[j] : bB[j - 4];
            a0 = fmaf(wa.x, xa0.x, a0);
            a0 = fmaf(wa.y, xa0.y, a0);
            a0 = fmaf(wa.z, xa0.z, a0);
            a0 = fmaf(wa.w, xa0.w, a0);
            a0 = fmaf(wb.x, xb0.x, a0);
            a0 = fmaf(wb.y, xb0.y, a0);
            a0 = fmaf(wb.z, xb0.z, a0);
            a0 = fmaf(wb.w, xb0.w, a0);
            h0[j] = fmaxf(a0, 0.f);
        }
        #pragma unroll
        for (int t = 0; t < 4; ++t)
            A[ks].u[t] = packbf(h0[2 * t], h0[2 * t + 1]);
    }

    const u32x4* wsB4 = (const u32x4*)wsB;

    #pragma unroll 1
    for (int head = 0; head < 2; ++head) {
        const float* b2 = head ? b22 : b21;
        const float* W3 = head ? W32 : W31;
        const float* b3 = head ? b32 : b31;

        f32x4 acc[8];
        #pragma unroll
        for (int nt = 0; nt < 8; ++nt) acc[nt] = (f32x4){0.f, 0.f, 0.f, 0.f};

        #pragma unroll
        for (int half = 0; half < 2; ++half) {
            // coalesced cooperative stage: 2048 frags (32 KB), ks in [half*4,half*4+4)
            const u32x4* src = wsB4 + head * 4096 + half * 2048;
            #pragma unroll
            for (int i = 0; i < 8; ++i) {
                int fi = (wave * 8 + i) * 64 + lane;
                stage[fi] = src[fi];
            }
            __syncthreads();
            #pragma unroll
            for (int ksl = 0; ksl < 4; ++ksl) {
                const int ks = half * 4 + ksl;
                Frag Bf[8];
                #pragma unroll
                for (int nt = 0; nt < 8; ++nt)
                    Bf[nt].q = stage[ksl * 512 + nt * 64 + lane];
                #pragma unroll
                for (int nt = 0; nt < 8; ++nt)
                    acc[nt] = __builtin_amdgcn_mfma_f32_16x16x32_bf16(A[ks].v, Bf[nt].v, acc[nt], 0, 0, 0);
            }
            __syncthreads();
        }

        // ---- epilogue: bias+relu+W3 dot, 16-lane reduce, LDS scatter
        float pr0[4], pr1[4];
        #pragma unroll
        for (int rg = 0; rg < 4; ++rg) { pr0[rg] = 0.f; pr1[rg] = 0.f; }
        #pragma unroll
        for (int nt = 0; nt < 8; ++nt) {
            int col = nt * 16 + m;
            float b2c = b2[col];
            float w0c = W3[col];
            float w1c = W3[128 + col];
            #pragma unroll
            for (int rg = 0; rg < 4; ++rg) {
                float rv = fmaxf(acc[nt][rg] + b2c, 0.f);
                pr0[rg] = fmaf(rv, w0c, pr0[rg]);
                pr1[rg] = fmaf(rv, w1c, pr1[rg]);
            }
        }
        #pragma unroll
        for (int rg = 0; rg < 4; ++rg) {
            float v0 = pr0[rg], v1 = pr1[rg];
            #pragma unroll
            for (int off = 1; off < 16; off <<= 1) {
                v0 += __shfl_xor(v0, off, 64);
                v1 += __shfl_xor(v1, off, 64);
            }
            pr0[rg] = v0; pr1[rg] = v1;
        }
        if (m == 0) {
            #pragma unroll
            for (int rg = 0; rg < 4; ++rg) {
                int row = wave * 16 + q * 4 + rg;
                float a0 = pr0[rg] + b3[0];
                float a1 = pr1[rg] + b3[1];
                if (head == 0) {
                    lds_p[row][0] = a0;
                    lds_p[row][1] = a1;
                } else {
                    lds_p[row][2] = 4.f / (1.f + __expf(-a0));
                    lds_p[row][3] = 4.f / (1.f + __expf(-a1));
                }
            }
        }
    }
    __syncthreads();

    // ================= QP tail (stage buffer reused) =================
    f32x4 (*qC)[64]  = (f32x4(*)[64])stage;           // 9 KB
    f32x4 (*res)[64] = (f32x4(*)[64])(stage + 576);   // 3 KB, after qC

    const int rq   = tid & 63;
    const int part = tid >> 6;
    const int R    = blockRow + rq;
    float p0 = lds_p[rq][0];
    float p1 = lds_p[rq][1];

    if (part == 0) {
        float s0 = lds_p[rq][2];
        float s1 = lds_p[rq][3];
        float xr[8];
        const float* xp = x + (R < Btot ? R : 0) * 8;
        #pragma unroll
        for (int c = 0; c < 8; ++c) xr[c] = fmaf(xp[c], stdp[c], meanp[c]);
        float px = xr[0], py = xr[1], th = xr[2], v = xr[3];
        float ox = xr[4], oy = xr[5], oth = xr[6], ov = xr[7];
        float st = __sinf(th),  ct = __cosf(th);
        float so = __sinf(oth), co = __cosf(oth);
        float vs = v * st, vc = v * ct;
        float sps = s0 + s1, ss = s0 * s1;
        float Lf2b = 2.f * v * v;
        #pragma unroll 1
        for (int k = 0; k < 8; ++k) {
            float dx = px - OBX[k], dy = py - OBY[k];
            float bar  = dx * dx + dy * dy - 0.64f;
            float bdot = 2.f * dx * vc + 2.f * dy * vs;
            float gx = 2.f * dx * vs - 2.f * dy * vc;
            float gy = -(2.f * dx * ct + 2.f * dy * st);
            float hk = Lf2b + sps * bdot + ss * bar;
            float ht = hk + 1e-6f * (1.f + fabsf(hk));
            qC[k][rq] = (f32x4){gx, gy, hk, ht};
        }
        {
            float dxo = px - ox, dyo = py - oy;
            float bar_o  = dxo * dxo + dyo * dyo - 0.25f;
            float bdot_o = 2.f * dxo * (vc - ov * co) + 2.f * dyo * (vs - ov * so);
            float Lf2b_o = 2.f * (v * v + ov * ov + 2.f * v * ov * __cosf(th - oth));
            float gx = 2.f * dxo * vs - 2.f * dyo * vc;
            float gy = -(2.f * dxo * ct + 2.f * dyo * st);
            float hk = Lf2b_o + sps * bdot_o + ss * bar_o;
            float ht = hk + 1e-6f * (1.f + fabsf(hk));
            qC[8][rq] = (f32x4){gx, gy, hk, ht};
        }
    }
    __syncthreads();

    // preload the 9 constraints into NAMED registers
    const f32x4 C0 = qC[0][rq], C1 = qC[1][rq], C2 = qC[2][rq];
    const f32x4 C3 = qC[3][rq], C4 = qC[4][rq], C5 = qC[5][rq];
    const f32x4 C6 = qC[6][rq], C7 = qC[7][rq], C8 = qC[8][rq];

    // candidates: 0 unconstrained, 1..9 singles, 10..45 pairs (triu order)
    // 4-way ordered split: [0,12) [12,24) [24,35) [35,46)
    const int c0i = (part == 0) ? 0  : (part == 1) ? 12 : (part == 2) ? 24 : 35;
    const int c1i = (part == 0) ? 12 : (part == 1) ? 24 : (part == 2) ? 35 : 46;
    float bobj = INFINITY;
    float bzx = -p0, bzy = -p1;     // argmin of all-inf -> index 0 -> z0
    #pragma unroll 2
    for (int c = c0i; c < c1i; ++c) {
        float zx, zy;
        bool pre;
        if (c == 0) {
            zx = -p0; zy = -p1; pre = true;
        } else if (c <= 9) {
            f32x4 g = qC[c - 1][rq];                 // one ds_read_b128
            float gg  = g.x * g.x + g.y * g.y;
            float lam = (-(g.x * p0 + g.y * p1) - g.z) / (gg + 1e-12f);
            zx = -p0 - lam * g.x;
            zy = -p1 - lam * g.y;
            pre = (lam >= -1e-8f);
        } else {
            int t = c - 10;
            int pi = unpack4(PI0_, PI1_, PI2_, t);   // scalar, no memory
            int pj = unpack4(PJ0_, PJ1_, PJ2_, t);
            f32x4 gi = qC[pi][rq];                   // two ds_read_b128
            f32x4 gj = qC[pj][rq];
            float det = gi.x * gj.y - gi.y * gj.x;
            bool dok = fabsf(det) > 1e-9f;
            float ds = dok ? det : 1.0f;
            float inv = 1.0f / ds;
            zx = (gi.z * gj.y - gj.z * gi.y) * inv;
            zy = (gi.x * gj.z - gj.x * gi.z) * inv;
            float rx = -(zx + p0), ry = -(zy + p1);
            float li = (gj.y * rx - gj.x * ry) * inv;
            float lj = (gi.x * ry - gi.y * rx) * inv;
            pre = dok && (li >= -1e-8f) && (lj >= -1e-8f);
        }
        bool ok = pre;
        ok = ok && (zx * C0.x + zy * C0.y <= C0.w);
        ok = ok && (zx * C1.x + zy * C1.y <= C1.w);
        ok = ok && (zx * C2.x + zy * C2.y <= C2.w);
        ok = ok && (zx * C3.x + zy * C3.y <= C3.w);
        ok = ok && (zx * C4.x + zy * C4.y <= C4.w);
        ok = ok && (zx * C5.x + zy * C5.y <= C5.w);
        ok = ok && (zx * C6.x + zy * C6.y <= C6.w);
        ok = ok && (zx * C7.x + zy * C7.y <= C7.w);
        ok = ok && (zx * C8.x + zy * C8.y <= C8.w);
        float obj = 0.5f * (zx * zx + zy * zy) + zx * p0 + zy * p1;
        if (ok && obj < bobj) { bobj = obj; bzx = zx; bzy = zy; }
    }

    if (part) {
        res[part - 1][rq] = (f32x4){bobj, bzx, bzy, 0.f};
    }
    __syncthreads();
    if (part == 0) {
        #pragma unroll
        for (int pp = 0; pp < 3; ++pp) {
            f32x4 r = res[pp][rq];
            if (r.x < bobj) { bobj = r.x; bzx = r.y; bzy = r.z; }  // strict <, ordered
        }
        if (R < Btot) {
            f32x2 o2; o2.x = bzx; o2.y = bzy;
            ((f32x2*)out)[R] = o2;
        }
    }
}

extern "C" void kernel_launch(void* const* d_in, const int* in_sizes, int n_in,
                              void* d_out, int out_size, void* d_ws, size_t ws_size,
                              hipStream_t stream) {
    const float* x    = (const float*)d_in[0];
    const float* mean = (const float*)d_in[1];
    const float* stdv = (const float*)d_in[2];
    const float* W1   = (const float*)d_in[3];
    const float* b1   = (const float*)d_in[4];
    const float* W21  = (const float*)d_in[5];
    const float* b21  = (const float*)d_in[6];
    const float* W31  = (const float*)d_in[7];
    const float* b31  = (const float*)d_in[8];
    const float* W22  = (const float*)d_in[9];
    const float* b22  = (const float*)d_in[10];
    const float* W32  = (const float*)d_in[11];
    const float* b32  = (const float*)d_in[12];
    int B = in_sizes[0] / 8;
    float* out = (float*)d_out;
    u32* ws = (u32*)d_ws;

    hipLaunchKernelGGL(prep_kernel, dim3(32), dim3(256), 0, stream, W21, W22, ws);

    hipLaunchKernelGGL(barriernet_kernel, dim3((B + 63) / 64), dim3(256), 0, stream,
                       x, mean, stdv, W1, b1, b21, W31, b31, b22, W32, b32,
                       ws, out, B);
}